// Round 3
// baseline (25662.357 us; speedup 1.0000x reference)
//
#include <hip/hip_runtime.h>
#include <hip/hip_bf16.h>

// Decoder: 128-step GRU + Luong attention, B=64, H=1024. Persistent kernel,
// 256 WGs x 256 thr (1 WG/CU), 2-level grid barrier, 5 phases/step.
// PRECISION: h-path GEMMs use 3-way bf16 splits (rep err 2^-27 < fp32 ulp)
// with 6 MFMA passes; bf16 products are exact in fp32 MFMA, so total error
// ~= fp32 accumulation noise. Attention scores/value in fp32 VALU (value
// pass sparse: skip softmax weights < 1e-8, error <= 1e-5).

#define NWG 256
#define NTHR 256
constexpr int BB = 64, TD = 128, TE = 256, HH = 1024, H3 = 3072;

typedef __attribute__((ext_vector_type(8))) __bf16 bf16x8;
typedef __attribute__((ext_vector_type(4))) float f32x4;
using bf = __hip_bfloat16;

__device__ __forceinline__ f32x4 mfma16(bf16x8 a, bf16x8 b, f32x4 c) {
  return __builtin_amdgcn_mfma_f32_16x16x32_bf16(a, b, c, 0, 0, 0);
}

struct Args {
  const float *x, *o_enc, *bfeed, *bxi, *bhr, *batt;
  const bf *Wf0, *Wf1, *Wf2, *Wh0, *Wh1, *Wh2;
  const bf *WxF0, *WxF1, *WxF2, *WxX0, *WxX1, *WxX2, *Wa0, *Wa1, *Wa2;
  float *h_f32;  // 2 planes (ping-pong) of 64*1024
  float *gxp;    // 4 * 64 * 3072 partials (reused as 4*64*1024 att partials)
  float *gh, *scores;
  bf *hs0, *hs1, *hs2, *ff0, *ff1, *ff2, *ifd0, *ifd1, *ifd2;
  bf *xt0, *xt1, *xt2, *vl0, *vl1, *vl2;
  unsigned *cnt, *cnt2, *go, *afl;
  float *out;
};

__device__ __forceinline__ void gbar(unsigned ep, const Args& a, int wg) {
  __syncthreads();
  if (threadIdx.x == 0) {
    __threadfence();
    unsigned* sub = a.cnt + (wg & 15) * 32;
    unsigned o = __hip_atomic_fetch_add(sub, 1u, __ATOMIC_ACQ_REL, __HIP_MEMORY_SCOPE_AGENT);
    if (o == 15) {
      __hip_atomic_store(sub, 0u, __ATOMIC_RELAXED, __HIP_MEMORY_SCOPE_AGENT);
      unsigned o2 = __hip_atomic_fetch_add(a.cnt2, 1u, __ATOMIC_ACQ_REL, __HIP_MEMORY_SCOPE_AGENT);
      if (o2 == 15) {
        __hip_atomic_store(a.cnt2, 0u, __ATOMIC_RELAXED, __HIP_MEMORY_SCOPE_AGENT);
        __hip_atomic_store(a.go, ep, __ATOMIC_RELEASE, __HIP_MEMORY_SCOPE_AGENT);
      }
    }
    while (__hip_atomic_load(a.go, __ATOMIC_RELAXED, __HIP_MEMORY_SCOPE_AGENT) < ep)
      __builtin_amdgcn_s_sleep(2);
    __threadfence();
  }
  __syncthreads();
}

__device__ __forceinline__ void split3_write(bf* p0, bf* p1, bf* p2, size_t i, float v) {
  bf b0 = __float2bfloat16(v);
  float r1 = v - __bfloat162float(b0);
  bf b1 = __float2bfloat16(r1);
  float r2 = r1 - __bfloat162float(b1);
  p0[i] = b0; p1[i] = b1; p2[i] = __float2bfloat16(r2);
}

// 6-pass split GEMM k-loop: captures all product terms >= 2^-18 exactly,
// residue ~2^-27. 4 accumulators break the MFMA dependence chain.
template <int K>
__device__ __forceinline__ f32x4 gemm6(const bf* A0, const bf* A1, const bf* A2,
                                       const bf* B0, const bf* B1, const bf* B2) {
  f32x4 c0 = {0.f, 0.f, 0.f, 0.f}, c1 = c0, c2 = c0, c3 = c0;
#pragma unroll 4
  for (int k = 0; k < K; k += 32) {
    bf16x8 a0 = *(const bf16x8*)(A0 + k);
    bf16x8 a1 = *(const bf16x8*)(A1 + k);
    bf16x8 a2 = *(const bf16x8*)(A2 + k);
    bf16x8 b0 = *(const bf16x8*)(B0 + k);
    bf16x8 b1 = *(const bf16x8*)(B1 + k);
    bf16x8 b2 = *(const bf16x8*)(B2 + k);
    c0 = mfma16(a0, b0, c0);
    c1 = mfma16(a0, b1, c1);
    c2 = mfma16(a1, b0, c2);
    c3 = mfma16(a1, b1, c3);
    c0 = mfma16(a0, b2, c0);
    c1 = mfma16(a2, b0, c1);
  }
  f32x4 s;
#pragma unroll
  for (int i = 0; i < 4; ++i) s[i] = (c0[i] + c1[i]) + (c2[i] + c3[i]);
  return s;
}

__global__ __launch_bounds__(NTHR, 1) void decoder_main(Args a) {
  const int wg = blockIdx.x;
  const int tid = threadIdx.x;
  const int lane = tid & 63;
  const int wv = tid >> 6;
  const int lrow = lane & 15;
  const int lkg = lane >> 4;

  __shared__ float s_h[HH];
  __shared__ float s_part[64][4];
  __shared__ float s_sm[TE];
  __shared__ float s_red[8];

  unsigned ep = 0;

  for (int t = 0; t < TD; ++t) {
    // ===== PH1: ffeed (WGs 0..63) / gh (WGs 64..255), 16 cols/WG =====
    {
      const bool isf = (wg < 64);
      const int j0 = (isf ? wg : wg - 64) * 16;
      const bf* A0 = isf ? a.ifd0 : a.hs0;
      const bf* A1 = isf ? a.ifd1 : a.hs1;
      const bf* A2 = isf ? a.ifd2 : a.hs2;
      const bf* B0 = isf ? a.Wf0 : a.Wh0;
      const bf* B1 = isf ? a.Wf1 : a.Wh1;
      const bf* B2 = isf ? a.Wf2 : a.Wh2;
      const size_t aoff = (size_t)(16 * wv + lrow) * HH + lkg * 8;
      const size_t boff = (size_t)(j0 + lrow) * HH + lkg * 8;
      f32x4 acc = gemm6<HH>(A0 + aoff, A1 + aoff, A2 + aoff, B0 + boff, B1 + boff, B2 + boff);
      const int col = j0 + lrow;
      if (isf) {
        float bia = a.bfeed[col];
#pragma unroll
        for (int r = 0; r < 4; ++r) {
          int row2 = 16 * wv + lkg * 4 + r;
          float f = tanhf(acc[r] + bia);
          split3_write(a.ff0, a.ff1, a.ff2, (size_t)row2 * HH + col, f);
        }
      } else {
        float bia = a.bhr[col];
#pragma unroll
        for (int r = 0; r < 4; ++r) {
          int row2 = 16 * wv + lkg * 4 + r;
          a.gh[(size_t)row2 * H3 + col] = acc[r] + bia;
        }
      }
    }
    gbar(++ep, a, wg);

    // ===== PH2: gx partials. wg=(jt 0..63, kq 0..3), K-slice 512 =====
    {
      const int jt = wg >> 2, kq = wg & 3;
      const int j0 = jt * 16;
      const bool isff = (kq < 2);
      const int koff = (kq & 1) * 512;
      const bf* A0 = isff ? a.ff0 : a.xt0;
      const bf* A1 = isff ? a.ff1 : a.xt1;
      const bf* A2 = isff ? a.ff2 : a.xt2;
      const bf* B0 = isff ? a.WxF0 : a.WxX0;
      const bf* B1 = isff ? a.WxF1 : a.WxX1;
      const bf* B2 = isff ? a.WxF2 : a.WxX2;
#pragma unroll
      for (int u = wv * 3; u < wv * 3 + 3; ++u) {
        const int g = u >> 2, mt = u & 3;
        const size_t aoff = (size_t)(mt * 16 + lrow) * HH + koff + lkg * 8;
        const size_t boff = (size_t)(g * HH + j0 + lrow) * HH + koff + lkg * 8;
        f32x4 acc = gemm6<512>(A0 + aoff, A1 + aoff, A2 + aoff, B0 + boff, B1 + boff, B2 + boff);
        const int gcol = g * HH + j0 + lrow;
#pragma unroll
        for (int r = 0; r < 4; ++r) {
          int grow = mt * 16 + lkg * 4 + r;
          a.gxp[(size_t)(kq * 64 + grow) * H3 + gcol] = acc[r];
        }
      }
    }
    gbar(++ep, a, wg);

    // ===== PH3: GRU pointwise (redundant x4) + scores + softmax + sparse value =====
    {
      const int b = wg >> 2, q = wg & 3;
      const float* hold = a.h_f32 + (size_t)(t & 1) * (BB * HH);
      float* hnew = a.h_f32 + (size_t)((t + 1) & 1) * (BB * HH);
      const float* ghb = a.gh + (size_t)b * H3;
#pragma unroll
      for (int i = 0; i < 4; ++i) {
        const int col = i * 256 + tid;
        float gz = a.bxi[col], gr = a.bxi[HH + col], gc = a.bxi[2 * HH + col];
#pragma unroll
        for (int kq = 0; kq < 4; ++kq) {
          const float* gp = a.gxp + (size_t)(kq * 64 + b) * H3;
          gz += gp[col]; gr += gp[HH + col]; gc += gp[2 * HH + col];
        }
        float z = 1.f / (1.f + expf(-(gz + ghb[col])));
        float rr = 1.f / (1.f + expf(-(gr + ghb[HH + col])));
        float hc = tanhf(gc + rr * ghb[2 * HH + col]);
        float hn = z * hold[(size_t)b * HH + col] + (1.f - z) * hc;
        s_h[col] = hn;
        if (q == 0) {
          hnew[(size_t)b * HH + col] = hn;
          split3_write(a.hs0, a.hs1, a.hs2, (size_t)b * HH + col, hn);
        }
      }
      __syncthreads();
      // scores: my 64 t's, k split 4-way
      {
        const int tt = tid & 63, kq4 = tid >> 6;
        const int tg = q * 64 + tt;
        const float* orow = a.o_enc + ((size_t)b * TE + tg) * HH + kq4 * 256;
        const float* hp = s_h + kq4 * 256;
        float s = 0.f;
        for (int k = 0; k < 256; k += 4) {
          f32x4 o4 = *(const f32x4*)(orow + k);
          s += o4[0] * hp[k] + o4[1] * hp[k + 1] + o4[2] * hp[k + 2] + o4[3] * hp[k + 3];
        }
        s_part[tt][kq4] = s;
      }
      __syncthreads();
      if (tid < 64)
        a.scores[(size_t)b * TE + q * 64 + tid] =
            s_part[tid][0] + s_part[tid][1] + s_part[tid][2] + s_part[tid][3];
      __syncthreads();
      if (tid == 0) {
        __threadfence();
        __hip_atomic_store(&a.afl[b * 4 + q], (unsigned)(t + 1),
                           __ATOMIC_RELEASE, __HIP_MEMORY_SCOPE_AGENT);
        for (int p = 1; p < 4; ++p) {
          unsigned idx = b * 4 + ((q + p) & 3);
          while (__hip_atomic_load(&a.afl[idx], __ATOMIC_RELAXED, __HIP_MEMORY_SCOPE_AGENT)
                 < (unsigned)(t + 1))
            __builtin_amdgcn_s_sleep(1);
        }
        __threadfence();
      }
      __syncthreads();
      float sc = a.scores[(size_t)b * TE + tid];
      float v = sc;
      for (int off = 32; off; off >>= 1) v = fmaxf(v, __shfl_xor(v, off));
      if (lane == 0) s_red[wv] = v;
      __syncthreads();
      float mx = fmaxf(fmaxf(s_red[0], s_red[1]), fmaxf(s_red[2], s_red[3]));
      float p = expf(sc - mx);
      float sum = p;
      for (int off = 32; off; off >>= 1) sum += __shfl_xor(sum, off);
      if (lane == 0) s_red[4 + wv] = sum;
      __syncthreads();
      float tot = s_red[4] + s_red[5] + s_red[6] + s_red[7];
      s_sm[tid] = p / tot;
      __syncthreads();
      // sparse value: my 256-col quarter; skip negligible weights (err <= 2.6e-6*|o|)
      {
        const int j = q * 256 + tid;
        const float* ob = a.o_enc + (size_t)b * TE * HH + j;
        float accv = 0.f;
        for (int tt2 = 0; tt2 < TE; ++tt2) {
          float w2 = s_sm[tt2];
          if (w2 > 1e-8f) accv += w2 * ob[(size_t)tt2 * HH];
        }
        split3_write(a.vl0, a.vl1, a.vl2, (size_t)b * HH + j, accv);
      }
    }
    gbar(++ep, a, wg);

    // ===== PH4: att GEMM partials. wg=(cu 0..63, kq 0..3), K-slice 512 =====
    {
      const int cu = wg >> 2, kq = wg & 3;
      const int j0 = cu * 16;
      const bool isv = (kq < 2);
      const int koff = (kq & 1) * 512;
      const bf* A0 = isv ? a.vl0 : a.hs0;
      const bf* A1 = isv ? a.vl1 : a.hs1;
      const bf* A2 = isv ? a.vl2 : a.hs2;
      const size_t aoff = (size_t)(16 * wv + lrow) * HH + koff + lkg * 8;
      const size_t boff = (size_t)(j0 + lrow) * 2048 + kq * 512 + lkg * 8;
      f32x4 acc = gemm6<512>(A0 + aoff, A1 + aoff, A2 + aoff,
                             a.Wa0 + boff, a.Wa1 + boff, a.Wa2 + boff);
      const int col = j0 + lrow;
#pragma unroll
      for (int r = 0; r < 4; ++r) {
        int row2 = 16 * wv + lkg * 4 + r;
        a.gxp[(size_t)(kq * 64 + row2) * 1024 + col] = acc[r];
      }
    }
    gbar(++ep, a, wg);

    // ===== PH5: att reduce + tanh -> out, ifeed; stage x_{t+1} =====
    {
      const int id = wg * NTHR + tid;
      const int row = id >> 10, col = id & 1023;
      float s = a.batt[col];
#pragma unroll
      for (int kq = 0; kq < 4; ++kq) s += a.gxp[(size_t)(kq * 64 + row) * 1024 + col];
      float hv = tanhf(s);
      a.out[((size_t)row * TD + t) * HH + col] = hv;
      split3_write(a.ifd0, a.ifd1, a.ifd2, (size_t)row * HH + col, hv);
      if (t + 1 < TD) {
        float xv = a.x[((size_t)row * TD + (t + 1)) * HH + col];
        split3_write(a.xt0, a.xt1, a.xt2, (size_t)id, xv);
      }
    }
    gbar(++ep, a, wg);
  }
}

// -------- prep kernels --------
__global__ void k_tr3(const float* src, bf* d0, bf* d1, bf* d2, int R, int C) {
  __shared__ float tile[32][33];
  int c0 = blockIdx.x * 32, r0 = blockIdx.y * 32;
  int tx = threadIdx.x & 31, ty = threadIdx.x >> 5;
  for (int i = ty; i < 32; i += 8)
    tile[i][tx] = src[(size_t)(r0 + i) * C + c0 + tx];
  __syncthreads();
  for (int i = ty; i < 32; i += 8) {
    float v = tile[tx][i];
    size_t o = (size_t)(c0 + i) * R + r0 + tx;
    bf b0 = __float2bfloat16(v);
    float r1 = v - __bfloat162float(b0);
    bf b1 = __float2bfloat16(r1);
    d0[o] = b0; d1[o] = b1; d2[o] = __float2bfloat16(r1 - __bfloat162float(b1));
  }
}

__global__ void k_init(const float* h_enc, float* h_f32, bf* h0, bf* h1, bf* h2,
                       bf* i0, bf* i1, bf* i2, const float* x, bf* x0, bf* x1, bf* x2) {
  int i = blockIdx.x * blockDim.x + threadIdx.x;
  float v = h_enc[i];
  h_f32[i] = v;
  split3_write(h0, h1, h2, i, v);
  bf z = __float2bfloat16(0.f);
  i0[i] = z; i1[i] = z; i2[i] = z;
  int row = i >> 10, col = i & 1023;
  split3_write(x0, x1, x2, i, x[((size_t)row * TD + 0) * HH + col]);
}

extern "C" void kernel_launch(void* const* d_in, const int* in_sizes, int n_in,
                              void* d_out, int out_size, void* d_ws, size_t ws_size,
                              hipStream_t stream) {
  const float* x     = (const float*)d_in[0];
  const float* o_enc = (const float*)d_in[1];
  const float* h_enc = (const float*)d_in[2];
  const float* Wfeed = (const float*)d_in[3];
  const float* bfeed = (const float*)d_in[4];
  const float* Wx    = (const float*)d_in[5];
  const float* Wh    = (const float*)d_in[6];
  const float* bxi   = (const float*)d_in[7];
  const float* bhr   = (const float*)d_in[8];
  const float* Watt  = (const float*)d_in[9];
  const float* batt  = (const float*)d_in[10];

  char* w = (char*)d_ws;
  auto alloc = [&](size_t b) { char* p = w; w += (b + 255) & ~255ULL; return p; };

  const size_t M1 = (size_t)1024 * 1024 * 2;  // 2 MB (1M bf16)
  bf* Wf[3];  for (auto& p : Wf)  p = (bf*)alloc(M1);
  bf* Wh_[3]; for (auto& p : Wh_) p = (bf*)alloc(3 * M1);
  bf* WxF[3]; for (auto& p : WxF) p = (bf*)alloc(3 * M1);
  bf* WxX[3]; for (auto& p : WxX) p = (bf*)alloc(3 * M1);
  bf* Wa[3];  for (auto& p : Wa)  p = (bf*)alloc(2 * M1);
  float* h_f32  = (float*)alloc((size_t)2 * BB * HH * 4);
  float* gxp    = (float*)alloc((size_t)4 * BB * H3 * 4);
  float* gh     = (float*)alloc((size_t)BB * H3 * 4);
  float* scores = (float*)alloc((size_t)BB * TE * 4);
  const size_t AB = (size_t)BB * HH * 2;
  bf *hs[3], *ff[3], *ifd[3], *xt[3], *vl[3];
  for (auto& p : hs)  p = (bf*)alloc(AB);
  for (auto& p : ff)  p = (bf*)alloc(AB);
  for (auto& p : ifd) p = (bf*)alloc(AB);
  for (auto& p : xt)  p = (bf*)alloc(AB);
  for (auto& p : vl)  p = (bf*)alloc(AB);
  unsigned* flags = (unsigned*)alloc(8192);

  hipMemsetAsync(flags, 0, 8192, stream);
  k_tr3<<<dim3(32, 32), 256, 0, stream>>>(Wfeed, Wf[0], Wf[1], Wf[2], 1024, 1024);
  k_tr3<<<dim3(96, 32), 256, 0, stream>>>(Wx, WxF[0], WxF[1], WxF[2], 1024, 3072);
  k_tr3<<<dim3(96, 32), 256, 0, stream>>>(Wx + (size_t)1024 * 3072, WxX[0], WxX[1], WxX[2], 1024, 3072);
  k_tr3<<<dim3(96, 32), 256, 0, stream>>>(Wh, Wh_[0], Wh_[1], Wh_[2], 1024, 3072);
  k_tr3<<<dim3(32, 64), 256, 0, stream>>>(Watt, Wa[0], Wa[1], Wa[2], 2048, 1024);
  k_init<<<BB * HH / 256, 256, 0, stream>>>(h_enc, h_f32, hs[0], hs[1], hs[2],
                                            ifd[0], ifd[1], ifd[2], x, xt[0], xt[1], xt[2]);

  Args a;
  a.x = x; a.o_enc = o_enc; a.bfeed = bfeed; a.bxi = bxi; a.bhr = bhr; a.batt = batt;
  a.Wf0 = Wf[0]; a.Wf1 = Wf[1]; a.Wf2 = Wf[2];
  a.Wh0 = Wh_[0]; a.Wh1 = Wh_[1]; a.Wh2 = Wh_[2];
  a.WxF0 = WxF[0]; a.WxF1 = WxF[1]; a.WxF2 = WxF[2];
  a.WxX0 = WxX[0]; a.WxX1 = WxX[1]; a.WxX2 = WxX[2];
  a.Wa0 = Wa[0]; a.Wa1 = Wa[1]; a.Wa2 = Wa[2];
  a.h_f32 = h_f32; a.gxp = gxp; a.gh = gh; a.scores = scores;
  a.hs0 = hs[0]; a.hs1 = hs[1]; a.hs2 = hs[2];
  a.ff0 = ff[0]; a.ff1 = ff[1]; a.ff2 = ff[2];
  a.ifd0 = ifd[0]; a.ifd1 = ifd[1]; a.ifd2 = ifd[2];
  a.xt0 = xt[0]; a.xt1 = xt[1]; a.xt2 = xt[2];
  a.vl0 = vl[0]; a.vl1 = vl[1]; a.vl2 = vl[2];
  a.cnt = flags; a.cnt2 = flags + 512; a.go = flags + 544; a.afl = flags + 576;
  a.out = (float*)d_out;

  decoder_main<<<NWG, NTHR, 0, stream>>>(a);
}

// Round 5
// 24123.743 us; speedup vs baseline: 1.0638x; 1.0638x over previous
//
#include <hip/hip_runtime.h>
#include <hip/hip_bf16.h>

// Decoder: 128-step GRU + Luong attention, B=64, H=1024. Persistent kernel,
// 256 WGs x 512 thr (8 waves/CU, 2/SIMD), 2-level grid barrier, 5 phases/step.
// NUMERICS (frozen from round 3, passed absmax 6.5e-3): 3-way bf16 splits,
// 6-pass MFMA (rep err 2^-27); fp32 state; fp32 o_enc attention; sparse value.
// ROUND 5 = ROUND 4 resubmit (round-4 bench died in infra push phase; kernel
// never ran): 2x occupancy (512-thr WGs), phases repartitioned to 2048 waves,
// coalesced wave-per-row score pass (1KB contiguous loads + shfl reduce).

#define NWG 256
#define NTHR 512
constexpr int BB = 64, TD = 128, TE = 256, HH = 1024, H3 = 3072;

typedef __attribute__((ext_vector_type(8))) __bf16 bf16x8;
typedef __attribute__((ext_vector_type(4))) float f32x4;
using bf = __hip_bfloat16;

__device__ __forceinline__ f32x4 mfma16(bf16x8 a, bf16x8 b, f32x4 c) {
  return __builtin_amdgcn_mfma_f32_16x16x32_bf16(a, b, c, 0, 0, 0);
}

struct Args {
  const float *x, *o_enc, *bfeed, *bxi, *bhr, *batt;
  const bf *Wf0, *Wf1, *Wf2, *Wh0, *Wh1, *Wh2;
  const bf *WxF0, *WxF1, *WxF2, *WxX0, *WxX1, *WxX2, *Wa0, *Wa1, *Wa2;
  float *h_f32;  // 2 planes ping-pong
  float *gxp;    // PH2 partials (2 planes of 64x3072); reused as PH4 attp (8 x 64x1024)
  float *gh, *scores;
  bf *hs0, *hs1, *hs2, *ff0, *ff1, *ff2, *ifd0, *ifd1, *ifd2;
  bf *xt0, *xt1, *xt2, *vl0, *vl1, *vl2;
  unsigned *cnt, *cnt2, *go, *afl;
  float *out;
};

__device__ __forceinline__ void gbar(unsigned ep, const Args& a, int wg) {
  __syncthreads();
  if (threadIdx.x == 0) {
    __threadfence();
    unsigned* sub = a.cnt + (wg & 15) * 32;
    unsigned o = __hip_atomic_fetch_add(sub, 1u, __ATOMIC_ACQ_REL, __HIP_MEMORY_SCOPE_AGENT);
    if (o == 15) {
      __hip_atomic_store(sub, 0u, __ATOMIC_RELAXED, __HIP_MEMORY_SCOPE_AGENT);
      unsigned o2 = __hip_atomic_fetch_add(a.cnt2, 1u, __ATOMIC_ACQ_REL, __HIP_MEMORY_SCOPE_AGENT);
      if (o2 == 15) {
        __hip_atomic_store(a.cnt2, 0u, __ATOMIC_RELAXED, __HIP_MEMORY_SCOPE_AGENT);
        __hip_atomic_store(a.go, ep, __ATOMIC_RELEASE, __HIP_MEMORY_SCOPE_AGENT);
      }
    }
    while (__hip_atomic_load(a.go, __ATOMIC_RELAXED, __HIP_MEMORY_SCOPE_AGENT) < ep)
      __builtin_amdgcn_s_sleep(2);
    __threadfence();
  }
  __syncthreads();
}

__device__ __forceinline__ void split3_write(bf* p0, bf* p1, bf* p2, size_t i, float v) {
  bf b0 = __float2bfloat16(v);
  float r1 = v - __bfloat162float(b0);
  bf b1 = __float2bfloat16(r1);
  float r2 = r1 - __bfloat162float(b1);
  p0[i] = b0; p1[i] = b1; p2[i] = __float2bfloat16(r2);
}

template <int K>
__device__ __forceinline__ f32x4 gemm6(const bf* A0, const bf* A1, const bf* A2,
                                       const bf* B0, const bf* B1, const bf* B2) {
  f32x4 c0 = {0.f, 0.f, 0.f, 0.f}, c1 = c0, c2 = c0, c3 = c0;
#pragma unroll 4
  for (int k = 0; k < K; k += 32) {
    bf16x8 a0 = *(const bf16x8*)(A0 + k);
    bf16x8 a1 = *(const bf16x8*)(A1 + k);
    bf16x8 a2 = *(const bf16x8*)(A2 + k);
    bf16x8 b0 = *(const bf16x8*)(B0 + k);
    bf16x8 b1 = *(const bf16x8*)(B1 + k);
    bf16x8 b2 = *(const bf16x8*)(B2 + k);
    c0 = mfma16(a0, b0, c0);
    c1 = mfma16(a0, b1, c1);
    c2 = mfma16(a1, b0, c2);
    c3 = mfma16(a1, b1, c3);
    c0 = mfma16(a0, b2, c0);
    c1 = mfma16(a2, b0, c1);
  }
  f32x4 s;
#pragma unroll
  for (int i = 0; i < 4; ++i) s[i] = (c0[i] + c1[i]) + (c2[i] + c3[i]);
  return s;
}

__global__ __launch_bounds__(NTHR, 2) void decoder_main(Args a) {
  const int wg = blockIdx.x;
  const int tid = threadIdx.x;
  const int lane = tid & 63;
  const int wv = tid >> 6;       // wave 0..7
  const int lrow = lane & 15;
  const int lkg = lane >> 4;

  __shared__ float s_acc[2][4][16][16];  // PH1: [K-half][M-tile][16][16]
  __shared__ float s_h[HH];
  __shared__ float s_sm[TE];
  __shared__ float s_red[8];
  __shared__ float s_val[2][256];

  unsigned ep = 0;

  for (int t = 0; t < TD; ++t) {
    // ===== PH1: ffeed (WGs 0..63) / gh (WGs 64..255); waves = (mt,kh) =====
    {
      const bool isf = (wg < 64);
      const int j0 = (isf ? wg : wg - 64) * 16;
      const bf* A0 = isf ? a.ifd0 : a.hs0;
      const bf* A1 = isf ? a.ifd1 : a.hs1;
      const bf* A2 = isf ? a.ifd2 : a.hs2;
      const bf* B0 = isf ? a.Wf0 : a.Wh0;
      const bf* B1 = isf ? a.Wf1 : a.Wh1;
      const bf* B2 = isf ? a.Wf2 : a.Wh2;
      const int mt = wv & 3, kh = wv >> 2;
      const size_t aoff = (size_t)(mt * 16 + lrow) * HH + kh * 512 + lkg * 8;
      const size_t boff = (size_t)(j0 + lrow) * HH + kh * 512 + lkg * 8;
      f32x4 acc = gemm6<512>(A0 + aoff, A1 + aoff, A2 + aoff, B0 + boff, B1 + boff, B2 + boff);
#pragma unroll
      for (int r = 0; r < 4; ++r) s_acc[kh][mt][lkg * 4 + r][lrow] = acc[r];
      __syncthreads();
#pragma unroll
      for (int e = tid; e < 1024; e += NTHR) {
        const int row = e >> 4, c = e & 15;
        const int emt = row >> 4, err2 = row & 15;
        float v = s_acc[0][emt][err2][c] + s_acc[1][emt][err2][c];
        const int col = j0 + c;
        if (isf) {
          float f = tanhf(v + a.bfeed[col]);
          split3_write(a.ff0, a.ff1, a.ff2, (size_t)row * HH + col, f);
        } else {
          a.gh[(size_t)row * H3 + col] = v + a.bhr[col];
        }
      }
    }
    gbar(++ep, a, wg);

    // ===== PH2: gx partials; 1536 wave-units (kh2, jt, g, mt), K=1024 =====
    if (wv < 6) {
      const int unit = wg * 6 + wv;
      const int kh2 = unit & 1;           // 0: ff half, 1: x half
      const int jt = (unit >> 1) & 63;
      const int gm = unit >> 7;           // 0..11
      const int g = gm >> 2, mt = gm & 3;
      const bf* A0 = kh2 ? a.xt0 : a.ff0;
      const bf* A1 = kh2 ? a.xt1 : a.ff1;
      const bf* A2 = kh2 ? a.xt2 : a.ff2;
      const bf* B0 = kh2 ? a.WxX0 : a.WxF0;
      const bf* B1 = kh2 ? a.WxX1 : a.WxF1;
      const bf* B2 = kh2 ? a.WxX2 : a.WxF2;
      const size_t aoff = (size_t)(mt * 16 + lrow) * HH + lkg * 8;
      const size_t boff = (size_t)(g * HH + jt * 16 + lrow) * HH + lkg * 8;
      f32x4 acc = gemm6<1024>(A0 + aoff, A1 + aoff, A2 + aoff, B0 + boff, B1 + boff, B2 + boff);
      const int gcol = g * 1024 + jt * 16 + lrow;
#pragma unroll
      for (int r = 0; r < 4; ++r)
        a.gxp[(size_t)(kh2 * 64 + mt * 16 + lkg * 4 + r) * H3 + gcol] = acc[r];
    }
    gbar(++ep, a, wg);

    // ===== PH3: GRU pointwise + scores + softmax + sparse value =====
    {
      const int b = wg >> 2, q = wg & 3;
      const float* hold = a.h_f32 + (size_t)(t & 1) * (BB * HH);
      float* hnew = a.h_f32 + (size_t)((t + 1) & 1) * (BB * HH);
      const float* ghb = a.gh + (size_t)b * H3;
#pragma unroll
      for (int ii = 0; ii < 2; ++ii) {
        const int col = ii * NTHR + tid;
        const float* g0 = a.gxp + (size_t)b * H3;
        const float* g1 = a.gxp + (size_t)(64 + b) * H3;
        float gz = a.bxi[col] + g0[col] + g1[col];
        float gr = a.bxi[HH + col] + g0[HH + col] + g1[HH + col];
        float gc = a.bxi[2 * HH + col] + g0[2 * HH + col] + g1[2 * HH + col];
        float z = 1.f / (1.f + expf(-(gz + ghb[col])));
        float rr = 1.f / (1.f + expf(-(gr + ghb[HH + col])));
        float hc = tanhf(gc + rr * ghb[2 * HH + col]);
        float hn = z * hold[(size_t)b * HH + col] + (1.f - z) * hc;
        s_h[col] = hn;
        if (q == 0) {
          hnew[(size_t)b * HH + col] = hn;
          split3_write(a.hs0, a.hs1, a.hs2, (size_t)b * HH + col, hn);
        }
      }
      __syncthreads();
      // scores: wave-per-row, lane owns k-chunks {l, l+64, l+128, l+192}*4 (coalesced 1KB)
      {
        f32x4 sh0 = *(const f32x4*)(s_h + 0 + lane * 4);
        f32x4 sh1 = *(const f32x4*)(s_h + 256 + lane * 4);
        f32x4 sh2 = *(const f32x4*)(s_h + 512 + lane * 4);
        f32x4 sh3 = *(const f32x4*)(s_h + 768 + lane * 4);
        const float* obase = a.o_enc + ((size_t)b * TE + q * 64 + wv * 8) * HH + lane * 4;
#pragma unroll 2
        for (int i = 0; i < 8; ++i) {
          const float* orow = obase + (size_t)i * HH;
          f32x4 o0 = *(const f32x4*)(orow);
          f32x4 o1 = *(const f32x4*)(orow + 256);
          f32x4 o2 = *(const f32x4*)(orow + 512);
          f32x4 o3 = *(const f32x4*)(orow + 768);
          float s = o0[0] * sh0[0] + o0[1] * sh0[1] + o0[2] * sh0[2] + o0[3] * sh0[3]
                  + o1[0] * sh1[0] + o1[1] * sh1[1] + o1[2] * sh1[2] + o1[3] * sh1[3]
                  + o2[0] * sh2[0] + o2[1] * sh2[1] + o2[2] * sh2[2] + o2[3] * sh2[3]
                  + o3[0] * sh3[0] + o3[1] * sh3[1] + o3[2] * sh3[2] + o3[3] * sh3[3];
          for (int off = 32; off; off >>= 1) s += __shfl_xor(s, off);
          if (lane == 0) a.scores[(size_t)b * TE + q * 64 + wv * 8 + i] = s;
        }
      }
      __syncthreads();
      if (tid == 0) {
        __threadfence();
        __hip_atomic_store(&a.afl[b * 4 + q], (unsigned)(t + 1),
                           __ATOMIC_RELEASE, __HIP_MEMORY_SCOPE_AGENT);
        for (int p = 1; p < 4; ++p) {
          unsigned idx = b * 4 + ((q + p) & 3);
          while (__hip_atomic_load(&a.afl[idx], __ATOMIC_RELAXED, __HIP_MEMORY_SCOPE_AGENT)
                 < (unsigned)(t + 1))
            __builtin_amdgcn_s_sleep(1);
        }
        __threadfence();
      }
      __syncthreads();
      // softmax over 256 (first 4 waves), uniform __syncthreads
      float sc = 0.f, p = 0.f;
      if (tid < 256) {
        sc = a.scores[(size_t)b * TE + tid];
        float v = sc;
        for (int off = 32; off; off >>= 1) v = fmaxf(v, __shfl_xor(v, off));
        if (lane == 0) s_red[wv] = v;
      }
      __syncthreads();
      {
        float mx = fmaxf(fmaxf(s_red[0], s_red[1]), fmaxf(s_red[2], s_red[3]));
        if (tid < 256) {
          p = expf(sc - mx);
          float sum = p;
          for (int off = 32; off; off >>= 1) sum += __shfl_xor(sum, off);
          if (lane == 0) s_red[4 + wv] = sum;
        }
      }
      __syncthreads();
      if (tid < 256) {
        float tot = s_red[4] + s_red[5] + s_red[6] + s_red[7];
        s_sm[tid] = p / tot;
      }
      __syncthreads();
      // sparse value: col j = q*256 + c, t-range split over th
      {
        const int c = tid & 255, th = tid >> 8;
        const int j = q * 256 + c;
        const float* ob = a.o_enc + (size_t)b * TE * HH + j;
        float accv = 0.f;
        for (int tt2 = th * 128; tt2 < th * 128 + 128; ++tt2) {
          float w2 = s_sm[tt2];
          if (w2 > 1e-8f) accv += w2 * ob[(size_t)tt2 * HH];
        }
        s_val[th][c] = accv;
      }
      __syncthreads();
      if (tid < 256)
        split3_write(a.vl0, a.vl1, a.vl2, (size_t)b * HH + q * 256 + tid,
                     s_val[0][tid] + s_val[1][tid]);
    }
    gbar(++ep, a, wg);

    // ===== PH4: att partials; 2048 wave-units: WG=(mt,cu), wave=kq8 (K=256) =====
    {
      const int kq8 = wv;
      const int cu = wg & 63;
      const int mt = wg >> 6;
      const bool isv = (kq8 < 4);
      const int koff = (kq8 & 3) * 256;
      const bf* A0 = isv ? a.vl0 : a.hs0;
      const bf* A1 = isv ? a.vl1 : a.hs1;
      const bf* A2 = isv ? a.vl2 : a.hs2;
      const size_t aoff = (size_t)(mt * 16 + lrow) * HH + koff + lkg * 8;
      const size_t boff = (size_t)(cu * 16 + lrow) * 2048 + kq8 * 256 + lkg * 8;
      f32x4 acc = gemm6<256>(A0 + aoff, A1 + aoff, A2 + aoff,
                             a.Wa0 + boff, a.Wa1 + boff, a.Wa2 + boff);
#pragma unroll
      for (int r = 0; r < 4; ++r)
        a.gxp[(size_t)(kq8 * 64 + mt * 16 + lkg * 4 + r) * 1024 + cu * 16 + lrow] = acc[r];
    }
    gbar(++ep, a, wg);

    // ===== PH5: att reduce + tanh -> out/ifd; spare threads stage x_{t+1} =====
    {
      const int id = wg * NTHR + tid;  // 0..131071
      if (id < 65536) {
        const int row = id >> 10, col = id & 1023;
        float s = a.batt[col];
#pragma unroll
        for (int kq = 0; kq < 8; ++kq) s += a.gxp[(size_t)(kq * 64 + row) * 1024 + col];
        float hv = tanhf(s);
        a.out[((size_t)row * TD + t) * HH + col] = hv;
        split3_write(a.ifd0, a.ifd1, a.ifd2, (size_t)row * HH + col, hv);
      } else if (t + 1 < TD) {
        const int id2 = id - 65536;
        const int row = id2 >> 10, col = id2 & 1023;
        split3_write(a.xt0, a.xt1, a.xt2, (size_t)id2,
                     a.x[((size_t)row * TD + (t + 1)) * HH + col]);
      }
    }
    gbar(++ep, a, wg);
  }
}

// -------- prep kernels --------
__global__ void k_tr3(const float* src, bf* d0, bf* d1, bf* d2, int R, int C) {
  __shared__ float tile[32][33];
  int c0 = blockIdx.x * 32, r0 = blockIdx.y * 32;
  int tx = threadIdx.x & 31, ty = threadIdx.x >> 5;
  for (int i = ty; i < 32; i += 8)
    tile[i][tx] = src[(size_t)(r0 + i) * C + c0 + tx];
  __syncthreads();
  for (int i = ty; i < 32; i += 8) {
    float v = tile[tx][i];
    size_t o = (size_t)(c0 + i) * R + r0 + tx;
    bf b0 = __float2bfloat16(v);
    float r1 = v - __bfloat162float(b0);
    bf b1 = __float2bfloat16(r1);
    d0[o] = b0; d1[o] = b1; d2[o] = __float2bfloat16(r1 - __bfloat162float(b1));
  }
}

__global__ void k_init(const float* h_enc, float* h_f32, bf* h0, bf* h1, bf* h2,
                       bf* i0, bf* i1, bf* i2, const float* x, bf* x0, bf* x1, bf* x2) {
  int i = blockIdx.x * blockDim.x + threadIdx.x;
  float v = h_enc[i];
  h_f32[i] = v;
  split3_write(h0, h1, h2, i, v);
  bf z = __float2bfloat16(0.f);
  i0[i] = z; i1[i] = z; i2[i] = z;
  int row = i >> 10, col = i & 1023;
  split3_write(x0, x1, x2, i, x[((size_t)row * TD + 0) * HH + col]);
}

extern "C" void kernel_launch(void* const* d_in, const int* in_sizes, int n_in,
                              void* d_out, int out_size, void* d_ws, size_t ws_size,
                              hipStream_t stream) {
  const float* x     = (const float*)d_in[0];
  const float* o_enc = (const float*)d_in[1];
  const float* h_enc = (const float*)d_in[2];
  const float* Wfeed = (const float*)d_in[3];
  const float* bfeed = (const float*)d_in[4];
  const float* Wx    = (const float*)d_in[5];
  const float* Wh    = (const float*)d_in[6];
  const float* bxi   = (const float*)d_in[7];
  const float* bhr   = (const float*)d_in[8];
  const float* Watt  = (const float*)d_in[9];
  const float* batt  = (const float*)d_in[10];

  char* w = (char*)d_ws;
  auto alloc = [&](size_t b) { char* p = w; w += (b + 255) & ~255ULL; return p; };

  const size_t M1 = (size_t)1024 * 1024 * 2;
  bf* Wf[3];  for (auto& p : Wf)  p = (bf*)alloc(M1);
  bf* Wh_[3]; for (auto& p : Wh_) p = (bf*)alloc(3 * M1);
  bf* WxF[3]; for (auto& p : WxF) p = (bf*)alloc(3 * M1);
  bf* WxX[3]; for (auto& p : WxX) p = (bf*)alloc(3 * M1);
  bf* Wa[3];  for (auto& p : Wa)  p = (bf*)alloc(2 * M1);
  float* h_f32  = (float*)alloc((size_t)2 * BB * HH * 4);
  float* gxp    = (float*)alloc((size_t)8 * BB * H3 * 4);  // covers PH2 (2 planes) + PH4 attp (8x64x1024)
  float* gh     = (float*)alloc((size_t)BB * H3 * 4);
  float* scores = (float*)alloc((size_t)BB * TE * 4);
  const size_t AB = (size_t)BB * HH * 2;
  bf *hs[3], *ff[3], *ifd[3], *xt[3], *vl[3];
  for (auto& p : hs)  p = (bf*)alloc(AB);
  for (auto& p : ff)  p = (bf*)alloc(AB);
  for (auto& p : ifd) p = (bf*)alloc(AB);
  for (auto& p : xt)  p = (bf*)alloc(AB);
  for (auto& p : vl)  p = (bf*)alloc(AB);
  unsigned* flags = (unsigned*)alloc(8192);

  hipMemsetAsync(flags, 0, 8192, stream);
  k_tr3<<<dim3(32, 32), 256, 0, stream>>>(Wfeed, Wf[0], Wf[1], Wf[2], 1024, 1024);
  k_tr3<<<dim3(96, 32), 256, 0, stream>>>(Wx, WxF[0], WxF[1], WxF[2], 1024, 3072);
  k_tr3<<<dim3(96, 32), 256, 0, stream>>>(Wx + (size_t)1024 * 3072, WxX[0], WxX[1], WxX[2], 1024, 3072);
  k_tr3<<<dim3(96, 32), 256, 0, stream>>>(Wh, Wh_[0], Wh_[1], Wh_[2], 1024, 3072);
  k_tr3<<<dim3(32, 64), 256, 0, stream>>>(Watt, Wa[0], Wa[1], Wa[2], 2048, 1024);
  k_init<<<BB * HH / 256, 256, 0, stream>>>(h_enc, h_f32, hs[0], hs[1], hs[2],
                                            ifd[0], ifd[1], ifd[2], x, xt[0], xt[1], xt[2]);

  Args a;
  a.x = x; a.o_enc = o_enc; a.bfeed = bfeed; a.bxi = bxi; a.bhr = bhr; a.batt = batt;
  a.Wf0 = Wf[0]; a.Wf1 = Wf[1]; a.Wf2 = Wf[2];
  a.Wh0 = Wh_[0]; a.Wh1 = Wh_[1]; a.Wh2 = Wh_[2];
  a.WxF0 = WxF[0]; a.WxF1 = WxF[1]; a.WxF2 = WxF[2];
  a.WxX0 = WxX[0]; a.WxX1 = WxX[1]; a.WxX2 = WxX[2];
  a.Wa0 = Wa[0]; a.Wa1 = Wa[1]; a.Wa2 = Wa[2];
  a.h_f32 = h_f32; a.gxp = gxp; a.gh = gh; a.scores = scores;
  a.hs0 = hs[0]; a.hs1 = hs[1]; a.hs2 = hs[2];
  a.ff0 = ff[0]; a.ff1 = ff[1]; a.ff2 = ff[2];
  a.ifd0 = ifd[0]; a.ifd1 = ifd[1]; a.ifd2 = ifd[2];
  a.xt0 = xt[0]; a.xt1 = xt[1]; a.xt2 = xt[2];
  a.vl0 = vl[0]; a.vl1 = vl[1]; a.vl2 = vl[2];
  a.cnt = flags; a.cnt2 = flags + 512; a.go = flags + 544; a.afl = flags + 576;
  a.out = (float*)d_out;

  decoder_main<<<NWG, NTHR, 0, stream>>>(a);
}